// Round 8
// baseline (164.344 us; speedup 1.0000x reference)
//
#include <hip/hip_runtime.h>

#define T_TOK 512
#define HID   2048
#define NEXP  16
#define IDIM  1024
#define KC    64
#define W2I   2048   // w13/w2 row width (fp32 elems); also gu row width

typedef __attribute__((ext_vector_type(8)))  short bf16x8;
typedef __attribute__((ext_vector_type(16))) float f32x16;
typedef __attribute__((ext_vector_type(4)))  float float4v;

__device__ __forceinline__ unsigned short f2bf(float f) {
    union { float f; unsigned u; } v; v.f = f;
    return (unsigned short)((v.u + 0x7FFFu + ((v.u >> 16) & 1u)) >> 16);
}

__device__ __forceinline__ bf16x8 pack8(const float* s) {
    bf16x8 r;
#pragma unroll
    for (int i = 0; i < 8; ++i) r[i] = (short)f2bf(s[i]);
    return r;
}

// ---------------- router: logits -> softmax -> top2; also x -> bf16 ----------------
__global__ __launch_bounds__(256) void router_kernel(
    const float* __restrict__ x, const float* __restrict__ rw,
    int* __restrict__ cnt, int* __restrict__ tok,
    int* __restrict__ rowid, float* __restrict__ wtrow,
    unsigned short* __restrict__ xb)
{
    int t = blockIdx.x;
    int tid = threadIdx.x;
    const float* xr = x + (size_t)t * HID;

    {
        int c = tid * 8;
        float4v a = *(const float4v*)(xr + c);
        float4v b = *(const float4v*)(xr + c + 4);
        float tmp[8];
#pragma unroll
        for (int i = 0; i < 4; ++i) { tmp[i] = a[i]; tmp[4 + i] = b[i]; }
        *(bf16x8*)(xb + (size_t)t * HID + c) = pack8(tmp);
    }

    float acc[NEXP];
#pragma unroll
    for (int e = 0; e < NEXP; ++e) acc[e] = 0.f;

    for (int k = tid; k < HID; k += 256) {
        float xv = xr[k];
#pragma unroll
        for (int e = 0; e < NEXP; ++e) acc[e] += xv * rw[e * HID + k];
    }

    __shared__ float red[4][NEXP];
    int lane = tid & 63, wv = tid >> 6;
#pragma unroll
    for (int e = 0; e < NEXP; ++e) {
        float v = acc[e];
#pragma unroll
        for (int off = 32; off > 0; off >>= 1) v += __shfl_down(v, off);
        if (lane == 0) red[wv][e] = v;
    }
    __syncthreads();

    if (tid == 0) {
        float l[NEXP];
        float mx = -1e30f;
#pragma unroll
        for (int e = 0; e < NEXP; ++e) {
            l[e] = red[0][e] + red[1][e] + red[2][e] + red[3][e];
            mx = fmaxf(mx, l[e]);
        }
        float s = 0.f;
#pragma unroll
        for (int e = 0; e < NEXP; ++e) { l[e] = __expf(l[e] - mx); s += l[e]; }
        float inv_s = 1.f / s;
        int i0 = 0; float v0 = -1.f;
        int i1 = 0; float v1 = -2.f;
#pragma unroll
        for (int e = 0; e < NEXP; ++e) {
            float p = l[e] * inv_s;
            if (p > v0)      { v1 = v0; i1 = i0; v0 = p; i0 = e; }
            else if (p > v1) { v1 = p; i1 = e; }
        }
        float inv = 1.f / (v0 + v1);
        int p0 = atomicAdd(&cnt[i0], 1);
        tok[i0 * T_TOK + p0] = t; rowid[i0 * T_TOK + p0] = 2 * t;
        int p1 = atomicAdd(&cnt[i1], 1);
        tok[i1 * T_TOK + p1] = t; rowid[i1 * T_TOK + p1] = 2 * t + 1;
        wtrow[2 * t]     = v0 * inv;
        wtrow[2 * t + 1] = v1 * inv;
    }
}

// ---------------- gemm1: gu[row][wcol] += x[row] . w13[e][:,wcol]  (k-chunked) ----
// grid 512: e = bid>>5, col-tile = (bid>>2)&7 (256 cols), k-chunk = bid&3 (512 k).
// 1024 threads = 16 waves (4M x 4N). M=128 tokens, N=256 wcols.
__global__ __launch_bounds__(1024, 4) void gemm1_kernel(
    const unsigned short* __restrict__ xb, const float* __restrict__ w13,
    const int* __restrict__ cnt, const int* __restrict__ tok,
    const int* __restrict__ rowid,
    float* __restrict__ gu)
{
    int bid = blockIdx.x;
    int e   = bid >> 5;
    int c0  = ((bid >> 2) & 7) * 256;
    int kc0 = (bid & 3) * 512;
    int n = cnt[e];
    int tid = threadIdx.x;

    __shared__ __align__(16) short Xs[128 * KC];   // 16 KB
    __shared__ __align__(16) short Ws[256 * KC];   // 32 KB
    __shared__ int tks[128];
    __shared__ int rws[128];

    int wcol = tid & 255, kq = (tid >> 8) & 3;     // 1 col x 16 k per thread
    const float* wsrc = w13 + (size_t)e * HID * W2I + c0 + wcol;
    int wswz = (wcol & 7) << 4;
    int xrow = tid >> 3, xq = tid & 7;             // 16 B of the 128 B row
    int xswz = (xrow & 7) << 4;

    int wave = tid >> 6, lane = tid & 63;
    int wm = wave & 3, wn = wave >> 2;
    int lrow = lane & 31, lhalf = lane >> 5;
    int swz = (lrow & 7) << 4;

    for (int t0 = 0; t0 < n; t0 += 128) {
        int nt = min(128, n - t0);
        __syncthreads();
        if (tid < 128) {
            int idx = t0 + min(tid, nt - 1);
            tks[tid] = tok[e * T_TOK + idx];
            rws[tid] = rowid[e * T_TOK + idx];
        }
        __syncthreads();

        const unsigned short* xsrc = xb + (size_t)tks[xrow] * HID + kc0 + xq * 8;

        f32x16 acc0 = (f32x16)0.f, acc1 = (f32x16)0.f;
        float  rW[16];
        bf16x8 rX;

#pragma unroll
        for (int j = 0; j < 16; ++j)
            rW[j] = wsrc[(size_t)(kc0 + kq * 16 + j) * W2I];
        rX = *(const bf16x8*)(xsrc);

        for (int p = 0; p < 8; ++p) {
            // stores (LDS free: barrier at loop end / tks barriers)
            *(bf16x8*)((char*)Ws + ((wcol * 128 + kq * 32)      ^ wswz)) = pack8(&rW[0]);
            *(bf16x8*)((char*)Ws + ((wcol * 128 + kq * 32 + 16) ^ wswz)) = pack8(&rW[8]);
            *(bf16x8*)((char*)Xs + ((xrow * 128 + xq * 16) ^ xswz)) = rX;
            // prefetch next phase (in flight across the MFMA)
            if (p < 7) {
                int k0n = kc0 + (p + 1) * KC;
#pragma unroll
                for (int j = 0; j < 16; ++j)
                    rW[j] = wsrc[(size_t)(k0n + kq * 16 + j) * W2I];
                rX = *(const bf16x8*)(xsrc + (p + 1) * KC);
            }
            __syncthreads();
            if (wm * 32 < nt) {
#pragma unroll
                for (int s = 0; s < 4; ++s) {
                    int kb = s * 32 + lhalf * 16;
                    bf16x8 a  = *(const bf16x8*)((char*)Xs + (((wm * 32 + lrow) * 128 + kb) ^ swz));
                    bf16x8 b0 = *(const bf16x8*)((char*)Ws + (((wn * 64 + lrow) * 128 + kb) ^ swz));
                    acc0 = __builtin_amdgcn_mfma_f32_32x32x16_bf16(a, b0, acc0, 0, 0, 0);
                    bf16x8 b1 = *(const bf16x8*)((char*)Ws + (((wn * 64 + 32 + lrow) * 128 + kb) ^ swz));
                    acc1 = __builtin_amdgcn_mfma_f32_32x32x16_bf16(a, b1, acc1, 0, 0, 0);
                }
            }
            __syncthreads();
        }

#pragma unroll
        for (int q = 0; q < 16; ++q) {
            int r = wm * 32 + (q & 3) + 8 * (q >> 2) + 4 * lhalf;
            if (r < nt) {
                size_t rowb = (size_t)rws[r] * W2I + c0 + wn * 64 + lrow;
                atomicAdd(&gu[rowb], acc0[q]);
                atomicAdd(&gu[rowb + 32], acc1[q]);
            }
        }
    }
}

// ---------------- silu pass: h[r][c] = wtrow[r] * silu(g) * u ----------------
__global__ __launch_bounds__(256) void silu_kernel(
    const float* __restrict__ gu, const float* __restrict__ wtrow,
    unsigned short* __restrict__ h)
{
    int r = blockIdx.x;            // 0..1023 (row id = 2t / 2t+1)
    int c = threadIdx.x * 4;       // 0..1023
    float w = wtrow[r];
    float4v g = *(const float4v*)(gu + (size_t)r * W2I + c);
    float4v u = *(const float4v*)(gu + (size_t)r * W2I + IDIM + c);
    unsigned o01, o23;
    float s0 = g[0] / (1.f + __expf(-g[0])) * u[0] * w;
    float s1 = g[1] / (1.f + __expf(-g[1])) * u[1] * w;
    float s2 = g[2] / (1.f + __expf(-g[2])) * u[2] * w;
    float s3 = g[3] / (1.f + __expf(-g[3])) * u[3] * w;
    o01 = (unsigned)f2bf(s0) | ((unsigned)f2bf(s1) << 16);
    o23 = (unsigned)f2bf(s2) | ((unsigned)f2bf(s3) << 16);
    unsigned* dst = (unsigned*)(h + (size_t)r * IDIM + c);
    dst[0] = o01; dst[1] = o23;
}

// ---------------- gemm2: out[t] += h[row] @ w2[e]  (k-chunked, atomic) ----------
// grid 512: e = bid>>5, col-tile = (bid>>2)&7 (256 out-cols), k-chunk = bid&3 (256 k).
__global__ __launch_bounds__(1024, 4) void gemm2_kernel(
    const unsigned short* __restrict__ h, const float* __restrict__ w2,
    const int* __restrict__ cnt, const int* __restrict__ tok,
    const int* __restrict__ rowid,
    float* __restrict__ out)
{
    int bid = blockIdx.x;
    int e   = bid >> 5;
    int c0  = ((bid >> 2) & 7) * 256;
    int kc0 = (bid & 3) * 256;
    int n = cnt[e];
    int tid = threadIdx.x;

    __shared__ __align__(16) short Xs[128 * KC];   // h rows, 16 KB
    __shared__ __align__(16) short Ws[256 * KC];   // w2 cols, 32 KB
    __shared__ int tks[128];
    __shared__ int rws[128];

    int wcol = tid & 255, kq = (tid >> 8) & 3;
    const float* wsrc = w2 + (size_t)e * IDIM * HID + c0 + wcol;
    int wswz = (wcol & 7) << 4;
    int xrow = tid >> 3, xq = tid & 7;
    int xswz = (xrow & 7) << 4;

    int wave = tid >> 6, lane = tid & 63;
    int wm = wave & 3, wn = wave >> 2;
    int lrow = lane & 31, lhalf = lane >> 5;
    int swz = (lrow & 7) << 4;

    for (int t0 = 0; t0 < n; t0 += 128) {
        int nt = min(128, n - t0);
        __syncthreads();
        if (tid < 128) {
            int idx = t0 + min(tid, nt - 1);
            tks[tid] = tok[e * T_TOK + idx];
            rws[tid] = rowid[e * T_TOK + idx];
        }
        __syncthreads();

        const unsigned short* xsrc = h + (size_t)rws[xrow] * IDIM + kc0 + xq * 8;

        f32x16 acc0 = (f32x16)0.f, acc1 = (f32x16)0.f;
        float  rW[16];
        bf16x8 rX;

#pragma unroll
        for (int j = 0; j < 16; ++j)
            rW[j] = wsrc[(size_t)(kc0 + kq * 16 + j) * W2I];
        rX = *(const bf16x8*)(xsrc);

        for (int p = 0; p < 4; ++p) {
            *(bf16x8*)((char*)Ws + ((wcol * 128 + kq * 32)      ^ wswz)) = pack8(&rW[0]);
            *(bf16x8*)((char*)Ws + ((wcol * 128 + kq * 32 + 16) ^ wswz)) = pack8(&rW[8]);
            *(bf16x8*)((char*)Xs + ((xrow * 128 + xq * 16) ^ xswz)) = rX;
            if (p < 3) {
                int k0n = kc0 + (p + 1) * KC;
#pragma unroll
                for (int j = 0; j < 16; ++j)
                    rW[j] = wsrc[(size_t)(k0n + kq * 16 + j) * W2I];
                rX = *(const bf16x8*)(xsrc + (p + 1) * KC);
            }
            __syncthreads();
            if (wm * 32 < nt) {
#pragma unroll
                for (int s = 0; s < 4; ++s) {
                    int kb = s * 32 + lhalf * 16;
                    bf16x8 a  = *(const bf16x8*)((char*)Xs + (((wm * 32 + lrow) * 128 + kb) ^ swz));
                    bf16x8 b0 = *(const bf16x8*)((char*)Ws + (((wn * 64 + lrow) * 128 + kb) ^ swz));
                    acc0 = __builtin_amdgcn_mfma_f32_32x32x16_bf16(a, b0, acc0, 0, 0, 0);
                    bf16x8 b1 = *(const bf16x8*)((char*)Ws + (((wn * 64 + 32 + lrow) * 128 + kb) ^ swz));
                    acc1 = __builtin_amdgcn_mfma_f32_32x32x16_bf16(a, b1, acc1, 0, 0, 0);
                }
            }
            __syncthreads();
        }

#pragma unroll
        for (int q = 0; q < 16; ++q) {
            int r = wm * 32 + (q & 3) + 8 * (q >> 2) + 4 * lhalf;
            if (r < nt) {
                size_t ob = (size_t)tks[r] * HID + c0 + wn * 64 + lrow;
                atomicAdd(&out[ob], acc0[q]);
                atomicAdd(&out[ob + 32], acc1[q]);
            }
        }
    }
}

extern "C" void kernel_launch(void* const* d_in, const int* in_sizes, int n_in,
                              void* d_out, int out_size, void* d_ws, size_t ws_size,
                              hipStream_t stream) {
    const float* x   = (const float*)d_in[0];   // [T, H]
    const float* rw  = (const float*)d_in[1];   // [E, H]
    const float* w13 = (const float*)d_in[2];   // [E, H, 2I]
    const float* w2  = (const float*)d_in[3];   // [E, I, H]
    float* out = (float*)d_out;                 // [T, H]

    char* ws = (char*)d_ws;
    int*   cnt   = (int*)ws;                         // 1 KB
    int*   tok   = (int*)(ws + 1024);                // 32 KB
    int*   rowid = (int*)(ws + 1024 + 32768);        // 32 KB
    float* wtrow = (float*)(ws + 1024 + 65536);      // 4 KB
    unsigned short* h  = (unsigned short*)(ws + 131072);            // [1024,1024] bf16 = 2 MB
    unsigned short* xb = (unsigned short*)(ws + 131072 + 2097152);  // [512,2048] bf16 = 2 MB
    float* gu = (float*)(ws + 131072 + 2 * 2097152);                // [1024,2048] f32 = 8 MB

    hipMemsetAsync(out, 0, (size_t)T_TOK * HID * sizeof(float), stream);
    hipMemsetAsync(cnt, 0, 1024, stream);
    hipMemsetAsync(gu, 0, (size_t)1024 * W2I * sizeof(float), stream);

    router_kernel<<<T_TOK, 256, 0, stream>>>(x, rw, cnt, tok, rowid, wtrow, xb);
    gemm1_kernel<<<512, 1024, 0, stream>>>(xb, w13, cnt, tok, rowid, gu);
    silu_kernel<<<1024, 256, 0, stream>>>(gu, wtrow, h);
    gemm2_kernel<<<512, 1024, 0, stream>>>(h, w2, cnt, tok, rowid, out);
}

// Round 9
// 146.076 us; speedup vs baseline: 1.1251x; 1.1251x over previous
//
#include <hip/hip_runtime.h>

#define T_TOK 512
#define HID   2048
#define NEXP  16
#define IDIM  1024

typedef __attribute__((ext_vector_type(8)))  short bf16x8;
typedef __attribute__((ext_vector_type(16))) float f32x16;
typedef __attribute__((ext_vector_type(4)))  float float4v;

__device__ __forceinline__ unsigned short f2bf(float f) {
    union { float f; unsigned u; } v; v.f = f;
    return (unsigned short)((v.u + 0x7FFFu + ((v.u >> 16) & 1u)) >> 16);
}

__device__ __forceinline__ bf16x8 pack8(const float* s) {
    bf16x8 r;
#pragma unroll
    for (int i = 0; i < 8; ++i) r[i] = (short)f2bf(s[i]);
    return r;
}

// ---------------- router: logits -> softmax -> top2; also x -> bf16 ----------------
__global__ __launch_bounds__(256) void router_kernel(
    const float* __restrict__ x, const float* __restrict__ rw,
    int* __restrict__ cnt, int* __restrict__ tok,
    int* __restrict__ rowid, float* __restrict__ wt,
    unsigned short* __restrict__ xb)
{
    int t = blockIdx.x;
    int tid = threadIdx.x;
    const float* xr = x + (size_t)t * HID;

    {
        int c = tid * 8;
        float4v a = *(const float4v*)(xr + c);
        float4v b = *(const float4v*)(xr + c + 4);
        float tmp[8];
#pragma unroll
        for (int i = 0; i < 4; ++i) { tmp[i] = a[i]; tmp[4 + i] = b[i]; }
        *(bf16x8*)(xb + (size_t)t * HID + c) = pack8(tmp);
    }

    float acc[NEXP];
#pragma unroll
    for (int e = 0; e < NEXP; ++e) acc[e] = 0.f;

    for (int k = tid; k < HID; k += 256) {
        float xv = xr[k];
#pragma unroll
        for (int e = 0; e < NEXP; ++e) acc[e] += xv * rw[e * HID + k];
    }

    __shared__ float red[4][NEXP];
    int lane = tid & 63, wv = tid >> 6;
#pragma unroll
    for (int e = 0; e < NEXP; ++e) {
        float v = acc[e];
#pragma unroll
        for (int off = 32; off > 0; off >>= 1) v += __shfl_down(v, off);
        if (lane == 0) red[wv][e] = v;
    }
    __syncthreads();

    if (tid == 0) {
        float l[NEXP];
        float mx = -1e30f;
#pragma unroll
        for (int e = 0; e < NEXP; ++e) {
            l[e] = red[0][e] + red[1][e] + red[2][e] + red[3][e];
            mx = fmaxf(mx, l[e]);
        }
        float s = 0.f;
#pragma unroll
        for (int e = 0; e < NEXP; ++e) { l[e] = __expf(l[e] - mx); s += l[e]; }
        float inv_s = 1.f / s;
        int i0 = 0; float v0 = -1.f;
        int i1 = 0; float v1 = -2.f;
#pragma unroll
        for (int e = 0; e < NEXP; ++e) {
            float p = l[e] * inv_s;
            if (p > v0)      { v1 = v0; i1 = i0; v0 = p; i0 = e; }
            else if (p > v1) { v1 = p; i1 = e; }
        }
        float inv = 1.f / (v0 + v1);
        int p0 = atomicAdd(&cnt[i0], 1);
        tok[i0 * T_TOK + p0] = t; rowid[i0 * T_TOK + p0] = 2 * t;     wt[i0 * T_TOK + p0] = v0 * inv;
        int p1 = atomicAdd(&cnt[i1], 1);
        tok[i1 * T_TOK + p1] = t; rowid[i1 * T_TOK + p1] = 2 * t + 1; wt[i1 * T_TOK + p1] = v1 * inv;
    }
}

// ---- X chunk staging: [128 rows][512 k] bf16 = 128KB, swizzled ----
#define STAGE_X(SRCROW) { \
    const bf16x8* src16 = (const bf16x8*)((SRCROW) + kc0 + xseg * 128); \
    _Pragma("unroll") \
    for (int q = 0; q < 16; ++q) { \
        bf16x8 v = src16[q]; \
        *(bf16x8*)((char*)Xs + ((xrow * 1024 + xseg * 256 + q * 16) ^ xswz)) = v; \
    } }

// ---- B-frag global load: 8 strided dwords (k-stride = 2048 fp32) ----
#define LOADB(buf, p_) { _Pragma("unroll") \
    for (int j = 0; j < 8; ++j) \
        buf[j] = wsrc[(size_t)(kc0 + (p_) * 16 + j) * 2048]; }

// ---------------- gemm1: h = wt * silu(x@Wg) * (x@Wu) -----------------------
// 256 blocks: e = bid>>4, tile = bid&15. Block: M=128 tokens x 64 gate + 64 up cols.
// 8 waves = 2 wm x 4 wn (wn 0-1 gate, 2-3 up); wave = 64 rows x 32 cols.
// W streams global->reg (no LDS, no barriers in phase loop). X in LDS per 512-k chunk.
__global__ __launch_bounds__(512, 2) void gemm1_kernel(
    const unsigned short* __restrict__ xb, const float* __restrict__ w13,
    const int* __restrict__ cnt, const int* __restrict__ tok,
    const int* __restrict__ rowid, const float* __restrict__ wt,
    unsigned short* __restrict__ h)
{
    int bid = blockIdx.x;
    int e    = bid >> 4;
    int tile = bid & 15;
    int n = cnt[e];
    int tid = threadIdx.x;

    __shared__ __align__(16) short Xs[65536];   // 128 KB: X chunk; reused as Ex at epilogue
    __shared__ int   tks[128];
    __shared__ int   rws[128];
    __shared__ float wts[128];

    int xrow = tid >> 2, xseg = tid & 3;
    int xswz = (xrow & 7) << 4;

    int wave = tid >> 6, lane = tid & 63;
    int wm = wave & 1, wn = wave >> 1;          // wm: 64-row half; wn: col group
    int lrow = lane & 31, hi = lane >> 5;
    int swz = (lrow & 7) << 4;

    int col = (wn < 2) ? (tile * 64 + wn * 32 + lrow)
                       : (IDIM + tile * 64 + (wn - 2) * 32 + lrow);
    const float* wsrc = w13 + (size_t)e * HID * 2048 + col + (size_t)hi * 8 * 2048;

    for (int t0 = 0; t0 < n; t0 += 128) {
        int nt = min(128, n - t0);
        __syncthreads();
        if (tid < 128) {
            int idx = t0 + min(tid, nt - 1);
            tks[tid] = tok[e * T_TOK + idx];
            rws[tid] = rowid[e * T_TOK + idx];
            wts[tid] = wt[e * T_TOK + idx];
        }
        __syncthreads();

        const unsigned short* xrowp = xb + (size_t)tks[xrow] * HID;
        bool g0 = (wm * 64) < nt, g1 = (wm * 64 + 32) < nt;
        int r0 = (wm * 64 + lrow) * 1024;
        int r1 = r0 + 32 * 1024;

        f32x16 acc0 = (f32x16)0.f, acc1 = (f32x16)0.f;

        for (int c = 0; c < 4; ++c) {
            int kc0 = c * 512;
            STAGE_X(xrowp);
            __syncthreads();

            float b0[8], b1[8];
            LOADB(b0, 0); LOADB(b1, 1);
#pragma unroll 4
            for (int p = 0; p < 32; p += 2) {
                bf16x8 bfr = pack8(b0);
                if (p + 2 < 32) LOADB(b0, p + 2);
                {
                    int kb = p * 32 + hi * 16;
                    bf16x8 a0 = *(const bf16x8*)((char*)Xs + ((r0 + kb) ^ swz));
                    bf16x8 a1 = *(const bf16x8*)((char*)Xs + ((r1 + kb) ^ swz));
                    if (g0) acc0 = __builtin_amdgcn_mfma_f32_32x32x16_bf16(a0, bfr, acc0, 0, 0, 0);
                    if (g1) acc1 = __builtin_amdgcn_mfma_f32_32x32x16_bf16(a1, bfr, acc1, 0, 0, 0);
                }
                bf16x8 bfr1 = pack8(b1);
                if (p + 3 < 32) LOADB(b1, p + 3);
                {
                    int kb = (p + 1) * 32 + hi * 16;
                    bf16x8 a0 = *(const bf16x8*)((char*)Xs + ((r0 + kb) ^ swz));
                    bf16x8 a1 = *(const bf16x8*)((char*)Xs + ((r1 + kb) ^ swz));
                    if (g0) acc0 = __builtin_amdgcn_mfma_f32_32x32x16_bf16(a0, bfr1, acc0, 0, 0, 0);
                    if (g1) acc1 = __builtin_amdgcn_mfma_f32_32x32x16_bf16(a1, bfr1, acc1, 0, 0, 0);
                }
                if ((p & 7) == 6) __builtin_amdgcn_s_barrier();  // raw resync, no drain
            }
            __syncthreads();   // X chunk consumed
        }

        // epilogue: exchange up-acc via Xs, gate waves write h
        float* Ex = (float*)Xs;
        if (wn >= 2) {
            int base = ((wm * 2 + (wn - 2)) * 2) * 1024;
#pragma unroll
            for (int q = 0; q < 16; ++q) {
                Ex[base + q * 64 + lane] = acc0[q];
                Ex[base + 1024 + q * 64 + lane] = acc1[q];
            }
        }
        __syncthreads();
        if (wn < 2) {
            int base = ((wm * 2 + wn) * 2) * 1024;
            int hcol = tile * 64 + wn * 32 + lrow;
#pragma unroll
            for (int q = 0; q < 16; ++q) {
                int crow = (q & 3) + 8 * (q >> 2) + 4 * hi;
                int ra = wm * 64 + crow;
                if (ra < nt) {
                    float g = acc0[q], u = Ex[base + q * 64 + lane];
                    float sg = g / (1.f + __expf(-g));
                    h[(size_t)rws[ra] * IDIM + hcol] = f2bf(wts[ra] * sg * u);
                }
                int rb = wm * 64 + 32 + crow;
                if (rb < nt) {
                    float g = acc1[q], u = Ex[base + 1024 + q * 64 + lane];
                    float sg = g / (1.f + __expf(-g));
                    h[(size_t)rws[rb] * IDIM + hcol] = f2bf(wts[rb] * sg * u);
                }
            }
        }
        __syncthreads();
    }
}

// ---------------- gemm2: out[t] += h[row] @ w2[e] ---------------------------
// 256 blocks: e = bid>>4, tile = bid&15 (128 out-cols). Same streaming structure.
__global__ __launch_bounds__(512, 2) void gemm2_kernel(
    const unsigned short* __restrict__ h, const float* __restrict__ w2,
    const int* __restrict__ cnt, const int* __restrict__ tok,
    const int* __restrict__ rowid,
    float* __restrict__ out)
{
    int bid = blockIdx.x;
    int e    = bid >> 4;
    int tile = bid & 15;
    int n = cnt[e];
    int tid = threadIdx.x;

    __shared__ __align__(16) short Xs[65536];   // 128 KB (only [128][512] used per chunk)
    __shared__ int tks[128];
    __shared__ int rws[128];

    int xrow = tid >> 2, xseg = tid & 3;
    int xswz = (xrow & 7) << 4;

    int wave = tid >> 6, lane = tid & 63;
    int wm = wave & 1, wn = wave >> 1;
    int lrow = lane & 31, hi = lane >> 5;
    int swz = (lrow & 7) << 4;

    int col = tile * 128 + wn * 32 + lrow;
    const float* wsrc = w2 + (size_t)e * IDIM * 2048 + col + (size_t)hi * 8 * 2048;

    for (int t0 = 0; t0 < n; t0 += 128) {
        int nt = min(128, n - t0);
        __syncthreads();
        if (tid < 128) {
            int idx = t0 + min(tid, nt - 1);
            tks[tid] = tok[e * T_TOK + idx];
            rws[tid] = rowid[e * T_TOK + idx];
        }
        __syncthreads();

        const unsigned short* xrowp = h + (size_t)rws[xrow] * IDIM;
        bool g0 = (wm * 64) < nt, g1 = (wm * 64 + 32) < nt;
        int r0 = (wm * 64 + lrow) * 1024;
        int r1 = r0 + 32 * 1024;

        f32x16 acc0 = (f32x16)0.f, acc1 = (f32x16)0.f;

        for (int c = 0; c < 2; ++c) {
            int kc0 = c * 512;
            STAGE_X(xrowp);
            __syncthreads();

            float b0[8], b1[8];
            LOADB(b0, 0); LOADB(b1, 1);
#pragma unroll 4
            for (int p = 0; p < 32; p += 2) {
                bf16x8 bfr = pack8(b0);
                if (p + 2 < 32) LOADB(b0, p + 2);
                {
                    int kb = p * 32 + hi * 16;
                    bf16x8 a0 = *(const bf16x8*)((char*)Xs + ((r0 + kb) ^ swz));
                    bf16x8 a1 = *(const bf16x8*)((char*)Xs + ((r1 + kb) ^ swz));
                    if (g0) acc0 = __builtin_amdgcn_mfma_f32_32x32x16_bf16(a0, bfr, acc0, 0, 0, 0);
                    if (g1) acc1 = __builtin_amdgcn_mfma_f32_32x32x16_bf16(a1, bfr, acc1, 0, 0, 0);
                }
                bf16x8 bfr1 = pack8(b1);
                if (p + 3 < 32) LOADB(b1, p + 3);
                {
                    int kb = (p + 1) * 32 + hi * 16;
                    bf16x8 a0 = *(const bf16x8*)((char*)Xs + ((r0 + kb) ^ swz));
                    bf16x8 a1 = *(const bf16x8*)((char*)Xs + ((r1 + kb) ^ swz));
                    if (g0) acc0 = __builtin_amdgcn_mfma_f32_32x32x16_bf16(a0, bfr1, acc0, 0, 0, 0);
                    if (g1) acc1 = __builtin_amdgcn_mfma_f32_32x32x16_bf16(a1, bfr1, acc1, 0, 0, 0);
                }
                if ((p & 7) == 6) __builtin_amdgcn_s_barrier();
            }
            __syncthreads();
        }

#pragma unroll
        for (int q = 0; q < 16; ++q) {
            int crow = (q & 3) + 8 * (q >> 2) + 4 * hi;
            int ra = wm * 64 + crow;
            if (ra < nt) atomicAdd(&out[(size_t)tks[ra] * HID + col], acc0[q]);
            int rb = wm * 64 + 32 + crow;
            if (rb < nt) atomicAdd(&out[(size_t)tks[rb] * HID + col], acc1[q]);
        }
        __syncthreads();
    }
}

extern "C" void kernel_launch(void* const* d_in, const int* in_sizes, int n_in,
                              void* d_out, int out_size, void* d_ws, size_t ws_size,
                              hipStream_t stream) {
    const float* x   = (const float*)d_in[0];   // [T, H]
    const float* rw  = (const float*)d_in[1];   // [E, H]
    const float* w13 = (const float*)d_in[2];   // [E, H, 2I]
    const float* w2  = (const float*)d_in[3];   // [E, I, H]
    float* out = (float*)d_out;                 // [T, H]

    char* ws = (char*)d_ws;
    int*   cnt   = (int*)ws;
    int*   tok   = (int*)(ws + 1024);
    int*   rowid = (int*)(ws + 1024 + 32768);
    float* wt    = (float*)(ws + 1024 + 65536);
    unsigned short* h  = (unsigned short*)(ws + 131072);            // [2T, I] bf16 = 2 MB
    unsigned short* xb = (unsigned short*)(ws + 131072 + 2097152);  // [T, H] bf16 = 2 MB

    hipMemsetAsync(out, 0, (size_t)T_TOK * HID * sizeof(float), stream);
    hipMemsetAsync(cnt, 0, 1024, stream);

    router_kernel<<<T_TOK, 256, 0, stream>>>(x, rw, cnt, tok, rowid, wt, xb);
    gemm1_kernel<<<256, 512, 0, stream>>>(xb, w13, cnt, tok, rowid, wt, h);
    gemm2_kernel<<<256, 512, 0, stream>>>(h, w2, cnt, tok, rowid, out);
}

// Round 10
// 131.791 us; speedup vs baseline: 1.2470x; 1.1084x over previous
//
#include <hip/hip_runtime.h>

#define T_TOK 512
#define HID   2048
#define NEXP  16
#define IDIM  1024
#define KC    64
#define WSTRIDE 2048   // row stride (fp32 elems) of both w13 ([H][2I]) and w2 ([I][H])

typedef __attribute__((ext_vector_type(8)))  short bf16x8;
typedef __attribute__((ext_vector_type(16))) float f32x16;
typedef __attribute__((ext_vector_type(4)))  float float4v;

__device__ __forceinline__ unsigned short f2bf(float f) {
    union { float f; unsigned u; } v; v.f = f;
    return (unsigned short)((v.u + 0x7FFFu + ((v.u >> 16) & 1u)) >> 16);
}

__device__ __forceinline__ bf16x8 pack8(const float* s) {
    bf16x8 r;
#pragma unroll
    for (int i = 0; i < 8; ++i) r[i] = (short)f2bf(s[i]);
    return r;
}

// LDS-only barrier: waits ds ops, NOT the global-load queue (no vmcnt drain).
#define LGKM_BAR() { asm volatile("s_waitcnt lgkmcnt(0)" ::: "memory"); \
    __builtin_amdgcn_s_barrier(); __builtin_amdgcn_sched_barrier(0); }

// ---------------- router (+ x -> bf16 conversion) ----------------
__global__ __launch_bounds__(256) void router_kernel(
    const float* __restrict__ x, const float* __restrict__ rw,
    int* __restrict__ cnt, int* __restrict__ tok,
    int* __restrict__ rowid, float* __restrict__ wt,
    unsigned short* __restrict__ xb)
{
    int t = blockIdx.x;
    int tid = threadIdx.x;
    const float* xr = x + (size_t)t * HID;

    {
        int c = tid * 8;
        float4v a = *(const float4v*)(xr + c);
        float4v b = *(const float4v*)(xr + c + 4);
        float tmp[8];
#pragma unroll
        for (int i = 0; i < 4; ++i) { tmp[i] = a[i]; tmp[4 + i] = b[i]; }
        *(bf16x8*)(xb + (size_t)t * HID + c) = pack8(tmp);
    }

    float acc[NEXP];
#pragma unroll
    for (int e = 0; e < NEXP; ++e) acc[e] = 0.f;

    for (int k = tid; k < HID; k += 256) {
        float xv = xr[k];
#pragma unroll
        for (int e = 0; e < NEXP; ++e) acc[e] += xv * rw[e * HID + k];
    }

    __shared__ float red[4][NEXP];
    int lane = tid & 63, wv = tid >> 6;
#pragma unroll
    for (int e = 0; e < NEXP; ++e) {
        float v = acc[e];
#pragma unroll
        for (int off = 32; off > 0; off >>= 1) v += __shfl_down(v, off);
        if (lane == 0) red[wv][e] = v;
    }
    __syncthreads();

    if (tid == 0) {
        float l[NEXP];
        float mx = -1e30f;
#pragma unroll
        for (int e = 0; e < NEXP; ++e) {
            l[e] = red[0][e] + red[1][e] + red[2][e] + red[3][e];
            mx = fmaxf(mx, l[e]);
        }
        float s = 0.f;
#pragma unroll
        for (int e = 0; e < NEXP; ++e) { l[e] = __expf(l[e] - mx); s += l[e]; }
        float inv_s = 1.f / s;
        int i0 = 0; float v0 = -1.f;
        int i1 = 0; float v1 = -2.f;
#pragma unroll
        for (int e = 0; e < NEXP; ++e) {
            float p = l[e] * inv_s;
            if (p > v0)      { v1 = v0; i1 = i0; v0 = p; i0 = e; }
            else if (p > v1) { v1 = p; i1 = e; }
        }
        float inv = 1.f / (v0 + v1);
        int p0 = atomicAdd(&cnt[i0], 1);
        tok[i0 * T_TOK + p0] = t; rowid[i0 * T_TOK + p0] = 2 * t;     wt[i0 * T_TOK + p0] = v0 * inv;
        int p1 = atomicAdd(&cnt[i1], 1);
        tok[i1 * T_TOK + p1] = t; rowid[i1 * T_TOK + p1] = 2 * t + 1; wt[i1 * T_TOK + p1] = v1 * inv;
    }
}

// ---- staging macros ----
// W role: wcol = tid&63 (1 col), kq = tid>>6 (8 k-rows). Coalesced 256B row reads,
// register transpose, single b128 swizzled store (0-conflict).
#define LOADW(r, kk_) { _Pragma("unroll") for (int j = 0; j < 8; ++j) \
    r[j] = wsrc[(size_t)((kk_) + kq * 8 + j) * WSTRIDE]; }

#define STOREW(r, bufi) { \
    *(bf16x8*)((char*)Ws[bufi] + ((wcol * 128 + kq * 16) ^ ((wcol & 7) << 4))) = pack8(r); }

// X/H role: xrow = tid>>2 (row), xq = tid&3 (32B quarter of the 128B bf16 row)
#define LOADX(r, kk_) { \
    r[0] = *(const bf16x8*)(xsrc + (kk_)); \
    r[1] = *(const bf16x8*)(xsrc + (kk_) + 8); }

#define STOREX(r, bufi) { \
    *(bf16x8*)((char*)Xs[bufi] + ((xrow * 128 + xq * 32)      ^ xswz)) = r[0]; \
    *(bf16x8*)((char*)Xs[bufi] + ((xrow * 128 + xq * 32 + 16) ^ xswz)) = r[1]; }

// ---------------- gemm1: h = wt * silu(x@Wg) * (x@Wu), 32x32x16 MFMA ----------------
// 512 blocks (XCD-swizzled): e = bid>>5, hcol-tile = (bid&31)*32. M=128 tokens.
// W-tile = 64 wcols (32 gate + 32 up). 8 waves = 4 M-strips x {gate, up}.
__global__ __launch_bounds__(512, 4) void gemm1_kernel(
    const unsigned short* __restrict__ xb, const float* __restrict__ w13,
    const int* __restrict__ cnt, const int* __restrict__ tok,
    const int* __restrict__ rowid, const float* __restrict__ wt,
    unsigned short* __restrict__ h)
{
    int b0 = blockIdx.x;
    int bid = (b0 & 7) * 64 + (b0 >> 3);   // XCD swizzle: same-expert blocks share an XCD
    int e   = bid >> 5;
    int c0h = (bid & 31) * 32;
    int n = cnt[e];
    int tid = threadIdx.x;

    __shared__ __align__(16) short Xs[2][128 * KC];   // [token][k], 16 KB each
    __shared__ __align__(16) short Ws[2][64 * KC];    // [wcol][k]: 0-31 gate, 32-63 up; 8 KB each
    __shared__ float Ex[4][16][64];                    // u-exchange, 16 KB
    __shared__ int   tks[128];
    __shared__ int   rws[128];
    __shared__ float wts[128];

    const float* wbase = w13 + (size_t)e * HID * (2 * IDIM);

    int wcol = tid & 63, kq = tid >> 6;
    const float* wsrc = wbase + ((wcol < 32) ? (c0h + wcol)
                                             : (IDIM + c0h + (wcol - 32)));
    int xrow = tid >> 2, xq = tid & 3;
    int xswz = (xrow & 7) << 4;

    int wave = tid >> 6, lane = tid & 63;
    int wm = wave & 3, wn = wave >> 2;       // M-strip, {0:gate, 1:up}
    int lrow = lane & 31, lhalf = lane >> 5;
    int swz = (lrow & 7) << 4;

#define G1_MFMA(bufi) { if (wm * 32 < nt) { _Pragma("unroll") \
    for (int s = 0; s < 4; ++s) { \
        int kb = s * 32 + lhalf * 16; \
        bf16x8 a = *(const bf16x8*)((char*)Xs[bufi] + (((wm * 32 + lrow) * 128 + kb) ^ swz)); \
        bf16x8 b = *(const bf16x8*)((char*)Ws[bufi] + (((wn * 32 + lrow) * 128 + kb) ^ swz)); \
        acc = __builtin_amdgcn_mfma_f32_32x32x16_bf16(a, b, acc, 0, 0, 0); \
    } } }

    for (int t0 = 0; t0 < n; t0 += 128) {
        int nt = min(128, n - t0);
        __syncthreads();
        if (tid < 128) {
            int idx = t0 + min(tid, nt - 1);
            tks[tid] = tok[e * T_TOK + idx];
            rws[tid] = rowid[e * T_TOK + idx];
            wts[tid] = wt[e * T_TOK + idx];
        }
        __syncthreads();

        const unsigned short* xsrc = xb + (size_t)tks[xrow] * HID + xq * 16;

        f32x16 acc = (f32x16)0.f;
        float  rWa[8], rWb[8];
        bf16x8 rXa[2], rXb[2];

        LOADW(rWa, 0);  LOADX(rXa, 0);
        LOADW(rWb, KC); LOADX(rXb, KC);
        STOREW(rWa, 0); STOREX(rXa, 0);     // vmcnt counted: rWb batch stays in flight
        LGKM_BAR();

        for (int p = 0; p < HID / KC; p += 2) {
            int kf0 = (p + 2) * KC, kf1 = (p + 3) * KC;
            if (kf0 < HID) { LOADW(rWa, kf0); LOADX(rXa, kf0); }  // issue k+2
            G1_MFMA(0);
            STOREW(rWb, 1); STOREX(rXb, 1);   // waits rWb only (counted), k+2 in flight
            LGKM_BAR();
            if (kf1 < HID) { LOADW(rWb, kf1); LOADX(rXb, kf1); }  // issue k+3
            G1_MFMA(1);
            if (kf0 < HID) { STOREW(rWa, 0); STOREX(rXa, 0); }
            LGKM_BAR();
        }

        // epilogue: u-waves -> LDS; g-waves compute silu(g)*u*wt -> h (bf16)
        if (wn == 1) {
#pragma unroll
            for (int q = 0; q < 16; ++q) Ex[wm][q][lane] = acc[q];
        }
        __syncthreads();
        if (wn == 0) {
#pragma unroll
            for (int q = 0; q < 16; ++q) {
                int r = wm * 32 + (q & 3) + 8 * (q >> 2) + 4 * lhalf;
                if (r < nt) {
                    float g = acc[q];
                    float u = Ex[wm][q][lane];
                    float sg = g / (1.f + __expf(-g));
                    h[(size_t)rws[r] * IDIM + c0h + lrow] = f2bf(wts[r] * sg * u);
                }
            }
        }
    }
}

// ---------------- gemm2: out[t] += h[row] @ w2[e], 32x32x16 MFMA ----------------
// 512 blocks (XCD-swizzled): e = bid>>5, outcol-tile = (bid&31)*64. M=128 rows.
__global__ __launch_bounds__(512, 4) void gemm2_kernel(
    const unsigned short* __restrict__ h, const float* __restrict__ w2,
    const int* __restrict__ cnt, const int* __restrict__ tok,
    const int* __restrict__ rowid,
    float* __restrict__ out)
{
    int b0 = blockIdx.x;
    int bid = (b0 & 7) * 64 + (b0 >> 3);
    int e  = bid >> 5;
    int c0 = (bid & 31) * 64;
    int n = cnt[e];
    int tid = threadIdx.x;

    __shared__ __align__(16) short Xs[2][128 * KC];   // h rows
    __shared__ __align__(16) short Ws[2][64 * KC];    // w2 cols
    __shared__ int   tks[128];
    __shared__ int   rws[128];

    const float* wbase = w2 + (size_t)e * IDIM * HID;

    int wcol = tid & 63, kq = tid >> 6;
    const float* wsrc = wbase + c0 + wcol;
    int xrow = tid >> 2, xq = tid & 3;
    int xswz = (xrow & 7) << 4;

    int wave = tid >> 6, lane = tid & 63;
    int wm = wave & 3, wn = wave >> 2;
    int lrow = lane & 31, lhalf = lane >> 5;
    int swz = (lrow & 7) << 4;

#define G2_MFMA(bufi) { if (wm * 32 < nt) { _Pragma("unroll") \
    for (int s = 0; s < 4; ++s) { \
        int kb = s * 32 + lhalf * 16; \
        bf16x8 a = *(const bf16x8*)((char*)Xs[bufi] + (((wm * 32 + lrow) * 128 + kb) ^ swz)); \
        bf16x8 b = *(const bf16x8*)((char*)Ws[bufi] + (((wn * 32 + lrow) * 128 + kb) ^ swz)); \
        acc = __builtin_amdgcn_mfma_f32_32x32x16_bf16(a, b, acc, 0, 0, 0); \
    } } }

    for (int t0 = 0; t0 < n; t0 += 128) {
        int nt = min(128, n - t0);
        __syncthreads();
        if (tid < 128) {
            int idx = t0 + min(tid, nt - 1);
            tks[tid] = tok[e * T_TOK + idx];
            rws[tid] = rowid[e * T_TOK + idx];
        }
        __syncthreads();

        const unsigned short* xsrc = h + (size_t)rws[xrow] * IDIM + xq * 16;

        f32x16 acc = (f32x16)0.f;
        float  rWa[8], rWb[8];
        bf16x8 rXa[2], rXb[2];

        LOADW(rWa, 0);  LOADX(rXa, 0);
        LOADW(rWb, KC); LOADX(rXb, KC);
        STOREW(rWa, 0); STOREX(rXa, 0);
        LGKM_BAR();

        for (int p = 0; p < IDIM / KC; p += 2) {
            int kf0 = (p + 2) * KC, kf1 = (p + 3) * KC;
            if (kf0 < IDIM) { LOADW(rWa, kf0); LOADX(rXa, kf0); }
            G2_MFMA(0);
            STOREW(rWb, 1); STOREX(rXb, 1);
            LGKM_BAR();
            if (kf1 < IDIM) { LOADW(rWb, kf1); LOADX(rXb, kf1); }
            G2_MFMA(1);
            if (kf0 < IDIM) { STOREW(rWa, 0); STOREX(rXa, 0); }
            LGKM_BAR();
        }

#pragma unroll
        for (int q = 0; q < 16; ++q) {
            int r = wm * 32 + (q & 3) + 8 * (q >> 2) + 4 * lhalf;
            if (r < nt)
                atomicAdd(&out[(size_t)tks[r] * HID + c0 + wn * 32 + lrow], acc[q]);
        }
    }
}

extern "C" void kernel_launch(void* const* d_in, const int* in_sizes, int n_in,
                              void* d_out, int out_size, void* d_ws, size_t ws_size,
                              hipStream_t stream) {
    const float* x   = (const float*)d_in[0];   // [T, H]
    const float* rw  = (const float*)d_in[1];   // [E, H]
    const float* w13 = (const float*)d_in[2];   // [E, H, 2I]
    const float* w2  = (const float*)d_in[3];   // [E, I, H]
    float* out = (float*)d_out;                 // [T, H]

    char* ws = (char*)d_ws;
    int*   cnt   = (int*)ws;
    int*   tok   = (int*)(ws + 1024);
    int*   rowid = (int*)(ws + 1024 + 32768);
    float* wt    = (float*)(ws + 1024 + 65536);
    unsigned short* h  = (unsigned short*)(ws + 131072);            // [2T, I] bf16
    unsigned short* xb = (unsigned short*)(ws + 131072 + 2097152);  // [T, H] bf16

    hipMemsetAsync(out, 0, (size_t)T_TOK * HID * sizeof(float), stream);
    hipMemsetAsync(cnt, 0, 1024, stream);

    router_kernel<<<T_TOK, 256, 0, stream>>>(x, rw, cnt, tok, rowid, wt, xb);
    gemm1_kernel<<<512, 512, 0, stream>>>(xb, w13, cnt, tok, rowid, wt, h);
    gemm2_kernel<<<512, 512, 0, stream>>>(h, w2, cnt, tok, rowid, out);
}

// Round 11
// 121.566 us; speedup vs baseline: 1.3519x; 1.0841x over previous
//
#include <hip/hip_runtime.h>

#define T_TOK 512
#define HID   2048
#define NEXP  16
#define IDIM  1024
#define KC    64
#define WSTRIDE 2048   // row stride (fp32 elems) of both w13 ([H][2I]) and w2 ([I][H])

typedef __attribute__((ext_vector_type(8)))  short bf16x8;
typedef __attribute__((ext_vector_type(16))) float f32x16;
typedef __attribute__((ext_vector_type(4)))  float float4v;

__device__ __forceinline__ unsigned short f2bf(float f) {
    union { float f; unsigned u; } v; v.f = f;
    return (unsigned short)((v.u + 0x7FFFu + ((v.u >> 16) & 1u)) >> 16);
}

__device__ __forceinline__ bf16x8 pack8(const float* s) {
    bf16x8 r;
#pragma unroll
    for (int i = 0; i < 8; ++i) r[i] = (short)f2bf(s[i]);
    return r;
}

// LDS-only barrier: waits ds ops, NOT the global-load queue (no vmcnt drain).
#define LGKM_BAR() { asm volatile("s_waitcnt lgkmcnt(0)" ::: "memory"); \
    __builtin_amdgcn_s_barrier(); __builtin_amdgcn_sched_barrier(0); }

// ---------------- router (+ x -> bf16 conversion) ----------------
__global__ __launch_bounds__(256) void router_kernel(
    const float* __restrict__ x, const float* __restrict__ rw,
    int* __restrict__ cnt, int* __restrict__ tok,
    int* __restrict__ rowid, float* __restrict__ wt,
    unsigned short* __restrict__ xb)
{
    int t = blockIdx.x;
    int tid = threadIdx.x;
    const float* xr = x + (size_t)t * HID;

    {
        int c = tid * 8;
        float4v a = *(const float4v*)(xr + c);
        float4v b = *(const float4v*)(xr + c + 4);
        float tmp[8];
#pragma unroll
        for (int i = 0; i < 4; ++i) { tmp[i] = a[i]; tmp[4 + i] = b[i]; }
        *(bf16x8*)(xb + (size_t)t * HID + c) = pack8(tmp);
    }

    float acc[NEXP];
#pragma unroll
    for (int e = 0; e < NEXP; ++e) acc[e] = 0.f;

    for (int k = tid; k < HID; k += 256) {
        float xv = xr[k];
#pragma unroll
        for (int e = 0; e < NEXP; ++e) acc[e] += xv * rw[e * HID + k];
    }

    __shared__ float red[4][NEXP];
    int lane = tid & 63, wv = tid >> 6;
#pragma unroll
    for (int e = 0; e < NEXP; ++e) {
        float v = acc[e];
#pragma unroll
        for (int off = 32; off > 0; off >>= 1) v += __shfl_down(v, off);
        if (lane == 0) red[wv][e] = v;
    }
    __syncthreads();

    if (tid == 0) {
        float l[NEXP];
        float mx = -1e30f;
#pragma unroll
        for (int e = 0; e < NEXP; ++e) {
            l[e] = red[0][e] + red[1][e] + red[2][e] + red[3][e];
            mx = fmaxf(mx, l[e]);
        }
        float s = 0.f;
#pragma unroll
        for (int e = 0; e < NEXP; ++e) { l[e] = __expf(l[e] - mx); s += l[e]; }
        float inv_s = 1.f / s;
        int i0 = 0; float v0 = -1.f;
        int i1 = 0; float v1 = -2.f;
#pragma unroll
        for (int e = 0; e < NEXP; ++e) {
            float p = l[e] * inv_s;
            if (p > v0)      { v1 = v0; i1 = i0; v0 = p; i0 = e; }
            else if (p > v1) { v1 = p; i1 = e; }
        }
        float inv = 1.f / (v0 + v1);
        int p0 = atomicAdd(&cnt[i0], 1);
        tok[i0 * T_TOK + p0] = t; rowid[i0 * T_TOK + p0] = 2 * t;     wt[i0 * T_TOK + p0] = v0 * inv;
        int p1 = atomicAdd(&cnt[i1], 1);
        tok[i1 * T_TOK + p1] = t; rowid[i1 * T_TOK + p1] = 2 * t + 1; wt[i1 * T_TOK + p1] = v1 * inv;
    }
}

// ---- staging macros ----
// W role: wcol = tid&63 (1 col), kq = tid>>6 (8 k-rows). Coalesced 256B row reads,
// NON-TEMPORAL (streaming, no cache allocation), register transpose, swizzled b128 store.
#define LOADW(r, kk_) { _Pragma("unroll") for (int j = 0; j < 8; ++j) \
    r[j] = __builtin_nontemporal_load(&wsrc[(size_t)((kk_) + kq * 8 + j) * WSTRIDE]); }

#define STOREW(r, bufi) { \
    *(bf16x8*)((char*)Ws[bufi] + ((wcol * 128 + kq * 16) ^ ((wcol & 7) << 4))) = pack8(r); }

// X/H role: xrow = tid>>2 (row), xq = tid&3 (32B quarter of the 128B bf16 row)
#define LOADX(r, kk_) { \
    r[0] = *(const bf16x8*)(xsrc + (kk_)); \
    r[1] = *(const bf16x8*)(xsrc + (kk_) + 8); }

#define STOREX(r, bufi) { \
    *(bf16x8*)((char*)Xs[bufi] + ((xrow * 128 + xq * 32)      ^ xswz)) = r[0]; \
    *(bf16x8*)((char*)Xs[bufi] + ((xrow * 128 + xq * 32 + 16) ^ xswz)) = r[1]; }

// ---------------- gemm1: h = wt * silu(x@Wg) * (x@Wu), 32x32x16 MFMA ----------------
// 512 blocks (XCD-swizzled): e = bid>>5, hcol-tile = (bid&31)*32. M=128 tokens.
// W-tile = 64 wcols (32 gate + 32 up). 8 waves = 4 M-strips x {gate, up}.
__global__ __launch_bounds__(512, 4) void gemm1_kernel(
    const unsigned short* __restrict__ xb, const float* __restrict__ w13,
    const int* __restrict__ cnt, const int* __restrict__ tok,
    const int* __restrict__ rowid, const float* __restrict__ wt,
    unsigned short* __restrict__ h)
{
    int b0 = blockIdx.x;
    int bid = (b0 & 7) * 64 + (b0 >> 3);   // XCD swizzle: same-expert blocks share an XCD
    int e   = bid >> 5;
    int c0h = (bid & 31) * 32;
    int n = cnt[e];
    int tid = threadIdx.x;

    __shared__ __align__(16) short Xs[2][128 * KC];   // [token][k], 16 KB each
    __shared__ __align__(16) short Ws[2][64 * KC];    // [wcol][k]: 0-31 gate, 32-63 up; 8 KB each
    __shared__ float Ex[4][16][64];                    // u-exchange, 16 KB
    __shared__ int   tks[128];
    __shared__ int   rws[128];
    __shared__ float wts[128];

    const float* wbase = w13 + (size_t)e * HID * (2 * IDIM);

    int wcol = tid & 63, kq = tid >> 6;
    const float* wsrc = wbase + ((wcol < 32) ? (c0h + wcol)
                                             : (IDIM + c0h + (wcol - 32)));
    int xrow = tid >> 2, xq = tid & 3;
    int xswz = (xrow & 7) << 4;

    int wave = tid >> 6, lane = tid & 63;
    int wm = wave & 3, wn = wave >> 2;       // M-strip, {0:gate, 1:up}
    int lrow = lane & 31, lhalf = lane >> 5;
    int swz = (lrow & 7) << 4;

#define G1_MFMA(bufi) { if (wm * 32 < nt) { _Pragma("unroll") \
    for (int s = 0; s < 4; ++s) { \
        int kb = s * 32 + lhalf * 16; \
        bf16x8 a = *(const bf16x8*)((char*)Xs[bufi] + (((wm * 32 + lrow) * 128 + kb) ^ swz)); \
        bf16x8 b = *(const bf16x8*)((char*)Ws[bufi] + (((wn * 32 + lrow) * 128 + kb) ^ swz)); \
        acc = __builtin_amdgcn_mfma_f32_32x32x16_bf16(a, b, acc, 0, 0, 0); \
    } } }

    for (int t0 = 0; t0 < n; t0 += 128) {
        int nt = min(128, n - t0);
        __syncthreads();
        if (tid < 128) {
            int idx = t0 + min(tid, nt - 1);
            tks[tid] = tok[e * T_TOK + idx];
            rws[tid] = rowid[e * T_TOK + idx];
            wts[tid] = wt[e * T_TOK + idx];
        }
        __syncthreads();

        const unsigned short* xsrc = xb + (size_t)tks[xrow] * HID + xq * 16;

        f32x16 acc = (f32x16)0.f;
        float  rWa[8], rWb[8];
        bf16x8 rXa[2], rXb[2];

        LOADW(rWa, 0);  LOADX(rXa, 0);
        LOADW(rWb, KC); LOADX(rXb, KC);
        STOREW(rWa, 0); STOREX(rXa, 0);     // vmcnt counted: rWb batch stays in flight
        LGKM_BAR();

        for (int p = 0; p < HID / KC; p += 2) {
            int kf0 = (p + 2) * KC, kf1 = (p + 3) * KC;
            if (kf0 < HID) { LOADW(rWa, kf0); LOADX(rXa, kf0); }  // issue k+2
            G1_MFMA(0);
            STOREW(rWb, 1); STOREX(rXb, 1);   // waits rWb only (counted), k+2 in flight
            LGKM_BAR();
            if (kf1 < HID) { LOADW(rWb, kf1); LOADX(rXb, kf1); }  // issue k+3
            G1_MFMA(1);
            if (kf0 < HID) { STOREW(rWa, 0); STOREX(rXa, 0); }
            LGKM_BAR();
        }

        // epilogue: u-waves -> LDS; g-waves compute silu(g)*u*wt -> h (bf16)
        if (wn == 1) {
#pragma unroll
            for (int q = 0; q < 16; ++q) Ex[wm][q][lane] = acc[q];
        }
        __syncthreads();
        if (wn == 0) {
#pragma unroll
            for (int q = 0; q < 16; ++q) {
                int r = wm * 32 + (q & 3) + 8 * (q >> 2) + 4 * lhalf;
                if (r < nt) {
                    float g = acc[q];
                    float u = Ex[wm][q][lane];
                    float sg = g / (1.f + __expf(-g));
                    h[(size_t)rws[r] * IDIM + c0h + lrow] = f2bf(wts[r] * sg * u);
                }
            }
        }
    }
}

// ---------------- gemm2: out[t] += h[row] @ w2[e], 32x32x16 MFMA ----------------
// 512 blocks (XCD-swizzled): e = bid>>5, outcol-tile = (bid&31)*64. M=128 rows.
__global__ __launch_bounds__(512, 4) void gemm2_kernel(
    const unsigned short* __restrict__ h, const float* __restrict__ w2,
    const int* __restrict__ cnt, const int* __restrict__ tok,
    const int* __restrict__ rowid,
    float* __restrict__ out)
{
    int b0 = blockIdx.x;
    int bid = (b0 & 7) * 64 + (b0 >> 3);
    int e  = bid >> 5;
    int c0 = (bid & 31) * 64;
    int n = cnt[e];
    int tid = threadIdx.x;

    __shared__ __align__(16) short Xs[2][128 * KC];   // h rows
    __shared__ __align__(16) short Ws[2][64 * KC];    // w2 cols
    __shared__ int   tks[128];
    __shared__ int   rws[128];

    const float* wbase = w2 + (size_t)e * IDIM * HID;

    int wcol = tid & 63, kq = tid >> 6;
    const float* wsrc = wbase + c0 + wcol;
    int xrow = tid >> 2, xq = tid & 3;
    int xswz = (xrow & 7) << 4;

    int wave = tid >> 6, lane = tid & 63;
    int wm = wave & 3, wn = wave >> 2;
    int lrow = lane & 31, lhalf = lane >> 5;
    int swz = (lrow & 7) << 4;

#define G2_MFMA(bufi) { if (wm * 32 < nt) { _Pragma("unroll") \
    for (int s = 0; s < 4; ++s) { \
        int kb = s * 32 + lhalf * 16; \
        bf16x8 a = *(const bf16x8*)((char*)Xs[bufi] + (((wm * 32 + lrow) * 128 + kb) ^ swz)); \
        bf16x8 b = *(const bf16x8*)((char*)Ws[bufi] + (((wn * 32 + lrow) * 128 + kb) ^ swz)); \
        acc = __builtin_amdgcn_mfma_f32_32x32x16_bf16(a, b, acc, 0, 0, 0); \
    } } }

    for (int t0 = 0; t0 < n; t0 += 128) {
        int nt = min(128, n - t0);
        __syncthreads();
        if (tid < 128) {
            int idx = t0 + min(tid, nt - 1);
            tks[tid] = tok[e * T_TOK + idx];
            rws[tid] = rowid[e * T_TOK + idx];
        }
        __syncthreads();

        const unsigned short* xsrc = h + (size_t)rws[xrow] * IDIM + xq * 16;

        f32x16 acc = (f32x16)0.f;
        float  rWa[8], rWb[8];
        bf16x8 rXa[2], rXb[2];

        LOADW(rWa, 0);  LOADX(rXa, 0);
        LOADW(rWb, KC); LOADX(rXb, KC);
        STOREW(rWa, 0); STOREX(rXa, 0);
        LGKM_BAR();

        for (int p = 0; p < IDIM / KC; p += 2) {
            int kf0 = (p + 2) * KC, kf1 = (p + 3) * KC;
            if (kf0 < IDIM) { LOADW(rWa, kf0); LOADX(rXa, kf0); }
            G2_MFMA(0);
            STOREW(rWb, 1); STOREX(rXb, 1);
            LGKM_BAR();
            if (kf1 < IDIM) { LOADW(rWb, kf1); LOADX(rXb, kf1); }
            G2_MFMA(1);
            if (kf0 < IDIM) { STOREW(rWa, 0); STOREX(rXa, 0); }
            LGKM_BAR();
        }

#pragma unroll
        for (int q = 0; q < 16; ++q) {
            int r = wm * 32 + (q & 3) + 8 * (q >> 2) + 4 * lhalf;
            if (r < nt)
                atomicAdd(&out[(size_t)tks[r] * HID + c0 + wn * 32 + lrow], acc[q]);
        }
    }
}

extern "C" void kernel_launch(void* const* d_in, const int* in_sizes, int n_in,
                              void* d_out, int out_size, void* d_ws, size_t ws_size,
                              hipStream_t stream) {
    const float* x   = (const float*)d_in[0];   // [T, H]
    const float* rw  = (const float*)d_in[1];   // [E, H]
    const float* w13 = (const float*)d_in[2];   // [E, H, 2I]
    const float* w2  = (const float*)d_in[3];   // [E, I, H]
    float* out = (float*)d_out;                 // [T, H]

    char* ws = (char*)d_ws;
    int*   cnt   = (int*)ws;
    int*   tok   = (int*)(ws + 1024);
    int*   rowid = (int*)(ws + 1024 + 32768);
    float* wt    = (float*)(ws + 1024 + 65536);
    unsigned short* h  = (unsigned short*)(ws + 131072);            // [2T, I] bf16
    unsigned short* xb = (unsigned short*)(ws + 131072 + 2097152);  // [T, H] bf16

    hipMemsetAsync(out, 0, (size_t)T_TOK * HID * sizeof(float), stream);
    hipMemsetAsync(cnt, 0, 1024, stream);

    router_kernel<<<T_TOK, 256, 0, stream>>>(x, rw, cnt, tok, rowid, wt, xb);
    gemm1_kernel<<<512, 512, 0, stream>>>(xb, w13, cnt, tok, rowid, wt, h);
    gemm2_kernel<<<512, 512, 0, stream>>>(h, w2, cnt, tok, rowid, out);
}